// Round 8
// baseline (201.427 us; speedup 1.0000x reference)
//
#include <hip/hip_runtime.h>
#include <math.h>

#define APM   32
#define NMOL  256
#define FEAT  100
#define NPAD  112
#define LAYERS 4
#define NTHREADS 1024
#define NWAVES   16
#define G_TBL 1024
#define TSTR  128            // table row stride (f32 elems)
#define X1STR 132            // sX1 row stride (f32 elems)

typedef _Float16 f16x8 __attribute__((ext_vector_type(8)));
typedef _Float16 f16x2 __attribute__((ext_vector_type(2)));
typedef float    f32x4 __attribute__((ext_vector_type(4)));
typedef float    f32x2 __attribute__((ext_vector_type(2)));

// per-layer f16 frag-weight block layout in ws (element offsets)
#define L1F_OFF 0        // lin1f  14336
#define L2F_OFF 14336    // lin2f  14336
#define LVF_OFF 28672    // linf   14336
#define LWTOT   43008    // per layer
#define WTOTAL  (4*LWTOT) // 172032 f16 = 344064 B

#define PREP_BLOCKS 672  // 172032/256
#define TBL_BLOCKS  128  // 32 per layer, 32 s-points per block

__device__ __forceinline__ float sspf(float x){
  // ssp(x) = log(1+e^x) - log2 (direct form, R5)
  return __logf(1.0f + __expf(x)) - 0.69314718056f;
}

// ---------------------------------------------------------------------------
// R7/R8: single prep launch. Blocks [0,672): weight->MFMA-B-frag conversion
// (validated R3 layout). Blocks [672,800): edge-filter table build with
// w1/w2/biases LDS-staged, 32 grid points per block:
//   tbl[l][s][f] = cc(d_s) * ( ssp(ea(d_s)@W1 + b1) @ W2 + b2 )[f]
// f in [100,128) stored 0 so gather feature-pad lanes read exact zeros.
// ---------------------------------------------------------------------------
__global__ __launch_bounds__(256) void prep_all(
    const float* __restrict__ lin1_w, const float* __restrict__ lin2_w,
    const float* __restrict__ lin_w,
    const float* __restrict__ mlp_w1, const float* __restrict__ mlp_b1,
    const float* __restrict__ mlp_w2, const float* __restrict__ mlp_b2,
    _Float16* __restrict__ outw, float* __restrict__ tbl)
{
  if (blockIdx.x < PREP_BLOCKS){
    int gid = blockIdx.x*256 + threadIdx.x;    // < 172032 exactly
    int l = gid / LWTOT;
    int r = gid - l*LWTOT;
    const float* W; int e;
    if (r < 14336)      { W = lin1_w + l*10000; e = r; }
    else if (r < 28672) { W = lin2_w + l*10000; e = r - 14336; }
    else                { W = lin_w  + l*10000; e = r - 28672; }
    int j = e & 7, L = (e >> 3) & 63, tile = e >> 9;
    int kc = tile / 7, nt = tile - kc*7;
    int k = kc*32 + ((L >> 4) << 3) + j;
    int f = nt*16 + (L & 15);
    float v = (k < 100 && f < FEAT) ? W[k*FEAT + f] : 0.0f;
    outw[gid] = (_Float16)v;
    return;
  }
  // ---- table segment ----
  __shared__ float sW2[10000];
  __shared__ float sW1[2500];
  __shared__ float sB1[100], sB2[100];
  __shared__ float sT[4][100];
  int bid = blockIdx.x - PREP_BLOCKS;
  int l = bid >> 5;                        // 32 blocks per layer
  int s0 = (bid & 31) * 32;
  int tid = threadIdx.x, wv = tid >> 6, lane = tid & 63;
  for (int i = tid; i < 10000; i += 256) sW2[i] = mlp_w2[l*10000 + i];
  for (int i = tid; i < 2500;  i += 256) sW1[i] = mlp_w1[l*2500 + i];
  if (tid < 100) sB1[tid] = mlp_b1[l*100 + tid];
  if (tid >= 128 && tid < 228) sB2[tid-128] = mlp_b2[l*100 + tid-128];
  __syncthreads();
  #pragma unroll 1
  for (int si = 0; si < 8; si++){
    int s = s0 + wv*8 + si;
    float d = 6.0f * (float)s / (float)(G_TBL - 1);
    float ea[25];
    #pragma unroll
    for (int g = 0; g < 25; g++){
      float u = d - 0.25f*(float)g;
      ea[g] = __expf(-8.0f*u*u);
    }
    #pragma unroll
    for (int kk = 0; kk < 2; kk++){
      int k = lane + kk*64;
      if (k < 100){
        float acc = sB1[k];
        #pragma unroll
        for (int g = 0; g < 25; g++)
          acc += ea[g] * sW1[g*100 + k];
        sT[wv][k] = sspf(acc);
      }
    }
    // wave-local LDS RAW: in-order DS + compiler lgkmcnt (validated R6)
    float cc = 0.5f*(__cosf(d*0.52359877559f) + 1.0f);
    #pragma unroll
    for (int ff = 0; ff < 2; ff++){
      int f = lane + ff*64;
      float o = 0.0f;
      if (f < 100){
        o = sB2[f];
        for (int k = 0; k < 100; k++)
          o += sT[wv][k] * sW2[k*100 + f];
        o *= cc;
      }
      tbl[((size_t)l*G_TBL + s)*TSTR + f] = o;   // f in [100,128) -> 0
    }
  }
}

__device__ __forceinline__ void cpw(_Float16* dst, const _Float16* src, int n16){
  const uint4* s = (const uint4*)src;
  uint4* d = (uint4*)dst;
  for (int i = threadIdx.x; i < n16; i += NTHREADS) d[i] = s[i];
}

// ---------------------------------------------------------------------------
// Whole network per molecule in one block. 1024 thr = 16 waves, 1 block/CU.
// R6 tabulated the edge MLP; R7 merged prep + dieted the gather. R7 FAILED
// with NaN: gather lanes 56..63 (fb=112..126) read sX1 cols 112..127 which
// the x1 GEMM never writes — 0*stale-NaN = NaN. R8 fix: lane<56 guard (pairs
// 0..111 exactly cover NPAD); lanes 56..63 write exact-zero f16x2 (doubles
// as the sAf k-pad refresh); sX1 pad cols zeroed at init defensively.
// MFMA layouts (validated R3): A: m=lane&15,k=(lane>>4)*8+j ; C/D:
// n=lane&15, m=(lane>>4)*4+r.
// ---------------------------------------------------------------------------
__global__ __launch_bounds__(1024)
__attribute__((amdgpu_waves_per_eu(4, 4)))
void schnet_mega(
    const int* __restrict__ z, const float* __restrict__ pos,
    const float* __restrict__ emb, const _Float16* __restrict__ wf,
    const float* __restrict__ tbl,
    const float* __restrict__ lin2_b, const float* __restrict__ lin_b,
    const float* __restrict__ out_w1, const float* __restrict__ out_b1,
    const float* __restrict__ out_w2, const float* __restrict__ out_b2,
    float* __restrict__ out)
{
  __shared__ __align__(16) _Float16 sWA[43008];     // lin1f|lin2f|linf (86KB)
  __shared__ __align__(16) _Float16 sAf[APM*136];   // A-frag f16 (h / agg)
  __shared__ __align__(16) _Float16 sBf[APM*136];   // A-frag f16 (t2)
  __shared__ __align__(16) float    sX1[APM*X1STR]; // x1 fp32 row-major
  __shared__ __align__(16) float    sH [APM*NPAD];  // h state fp32
  __shared__ float sD [APM*33];
  __shared__ float sB2l[NPAD], sBlv[NPAD];
  __shared__ float sPos[APM*3];
  __shared__ float sPart[NWAVES];

  int tid = threadIdx.x, lane = tid & 63, wv = tid >> 6;
  int q = lane >> 4, n = lane & 15;
  int mol = blockIdx.x, mb = mol*APM;

  // ---------------- init ----------------
  if (tid < 96) sPos[tid] = pos[mb*3 + tid];
  if (tid < 512){                              // zero sBf k-pad cols 112..127
    int r0 = tid >> 4, c0 = 112 + (tid & 15);
    sBf[r0*136 + c0] = (_Float16)0.0f;
  }
  if (tid >= 512 && tid < 512 + APM*20){       // zero sX1 pad cols 112..131
    int i = tid - 512;
    int r = i/20, c = 112 + (i - r*20);
    sX1[r*X1STR + c] = 0.0f;
  }
  for (int i = tid; i < APM*136; i += NTHREADS){ // h init (fp32 + f16 frag)
    int r = i/136, c = i - r*136;
    float v = (c < FEAT) ? emb[z[mb+r]*FEAT + c] : 0.0f;
    sAf[i] = (_Float16)v;
    if (c < NPAD) sH[r*NPAD + c] = v;
  }
  __syncthreads();
  for (int p = tid; p < APM*APM; p += NTHREADS){  // distances
    int i = p >> 5, j = p & 31;
    float dx = sPos[i*3+0]-sPos[j*3+0];
    float dy = sPos[i*3+1]-sPos[j*3+1];
    float dz = sPos[i*3+2]-sPos[j*3+2];
    float d2 = dx*dx + dy*dy + dz*dz;
    sD[i*33+j] = (d2 > 36.0f) ? 6.0f : sqrtf(d2);
  }
  __syncthreads();
  if (tid < APM){                  // drop self + 3 farthest: d := 6.0 (tbl~0)
    float dd[32];
    #pragma unroll
    for (int j = 0; j < 32; j++) dd[j] = sD[tid*33+j];
    dd[tid] = 1e30f;
    unsigned dropped = 0u;
    for (int rr = 0; rr < 4; rr++){
      float mx = -1.0f; int mj = 0;
      #pragma unroll
      for (int j = 0; j < 32; j++){
        bool ok = !((dropped>>j)&1u) && (dd[j] > mx);
        mx = ok ? dd[j] : mx;  mj = ok ? j : mj;
      }
      dropped |= 1u << mj;
    }
    #pragma unroll
    for (int j = 0; j < 32; j++)
      if ((dropped>>j)&1u) sD[tid*33+j] = 6.0f;
  }
  __syncthreads();

  // ---------------- interaction layers ----------------
  for (int l = 0; l < LAYERS; l++){
    const _Float16* wl = wf + l*LWTOT;
    const float* tb = tbl + (size_t)l*G_TBL*TSTR;
    // ---- A: stage lin1f + biases ----
    cpw(sWA, wl + L1F_OFF, 14336/8);
    if (tid < 224){
      int w = tid/112, i = tid - w*112;
      float v = (i < FEAT) ? (w==0 ? lin2_b : lin_b)[l*FEAT + i] : 0.0f;
      (w==0 ? sB2l : sBlv)[i] = v;
    }
    __syncthreads();
    // ---- B: x1 = h @ lin1 -> sX1 row-major fp32 ----
    for (int tau = wv; tau < 14; tau += NWAVES){
      int mt = tau/7, nt = tau - mt*7;
      f32x4 acc = {0.0f,0.0f,0.0f,0.0f};
      #pragma unroll
      for (int kc = 0; kc < 4; kc++){
        f16x8 a = *(const f16x8*)&sAf[(mt*16+n)*136 + kc*32 + q*8];
        f16x8 b = *(const f16x8*)&sWA[((kc*7+nt)*64 + lane)*8];
        acc = __builtin_amdgcn_mfma_f32_16x16x32_f16(a, b, acc, 0, 0, 0);
      }
      #pragma unroll
      for (int r = 0; r < 4; r++)
        sX1[(mt*16+q*4+r)*X1STR + nt*16+n] = acc[r];
    }
    __syncthreads();
    // ---- C: stage lin2f+linf (overlaps gather) + CFConv table gather ----
    cpw(sWA + 14336, wl + L2F_OFF, 28672/8);
    {
      int fb = 2*lane;                       // feature pair (fb, fb+1)
      const float* rpb = tb + fb;
      #pragma unroll 1
      for (int t = 0; t < 2; t++){
        int a = wv*2 + t;
        if (lane < 56){                      // pairs 0..111 == NPAD exactly
          f32x2 agg = {0.0f, 0.0f};
          #pragma unroll 1
          for (int j0 = 0; j0 < 32; j0 += 4){
            float frv[4]; f32x2 w0[4], w1[4];
            #pragma unroll
            for (int u = 0; u < 4; u++){
              float d = sD[a*33 + j0 + u];   // wave-uniform broadcast
              float un = d * (float)((G_TBL-1)/6.0);
              int s = (int)un;
              s = (s > G_TBL-2) ? (G_TBL-2) : s;
              frv[u] = un - (float)s;
              const float* rp = rpb + s*TSTR;
              w0[u] = *(const f32x2*)rp;
              w1[u] = *(const f32x2*)(rp + TSTR);
            }
            #pragma unroll
            for (int u = 0; u < 4; u++){
              f32x2 w = w0[u] + frv[u]*(w1[u] - w0[u]);
              f32x2 x = *(const f32x2*)&sX1[(j0+u)*X1STR + fb];
              agg += w * x;
            }
          }
          *(f16x2*)&sAf[a*136 + fb] =
              (f16x2){(_Float16)agg.x, (_Float16)agg.y};
        } else {
          // fb in [112,126]: k-pad cols 112..127 refreshed to exact zero
          *(f16x2*)&sAf[a*136 + fb] = (f16x2){(_Float16)0.0f, (_Float16)0.0f};
        }
      }
    }
    __syncthreads();
    // ---- D: t2 = ssp(agg @ lin2 + b2l) -> sBf f16 ----
    for (int tau = wv; tau < 14; tau += NWAVES){
      int mt = tau/7, nt = tau - mt*7;
      f32x4 acc = {0.0f,0.0f,0.0f,0.0f};
      #pragma unroll
      for (int kc = 0; kc < 4; kc++){
        f16x8 a = *(const f16x8*)&sAf[(mt*16+n)*136 + kc*32 + q*8];
        f16x8 b = *(const f16x8*)&sWA[14336 + ((kc*7+nt)*64 + lane)*8];
        acc = __builtin_amdgcn_mfma_f32_16x16x32_f16(a, b, acc, 0, 0, 0);
      }
      float bb = sB2l[nt*16+n];
      #pragma unroll
      for (int r = 0; r < 4; r++)
        sBf[(mt*16+q*4+r)*136 + nt*16+n] = (_Float16)sspf(acc[r] + bb);
    }
    __syncthreads();
    // ---- E: v = t2 @ lin + bl ; h += v ; sAf = f16(h) ----
    for (int tau = wv; tau < 14; tau += NWAVES){
      int mt = tau/7, nt = tau - mt*7;
      f32x4 acc = {0.0f,0.0f,0.0f,0.0f};
      #pragma unroll
      for (int kc = 0; kc < 4; kc++){
        f16x8 a = *(const f16x8*)&sBf[(mt*16+n)*136 + kc*32 + q*8];
        f16x8 b = *(const f16x8*)&sWA[28672 + ((kc*7+nt)*64 + lane)*8];
        acc = __builtin_amdgcn_mfma_f32_16x16x32_f16(a, b, acc, 0, 0, 0);
      }
      int f = nt*16 + n;
      if (f < FEAT){
        float bb = sBlv[f];
        #pragma unroll
        for (int r = 0; r < 4; r++){
          int row = mt*16 + q*4 + r;
          float hn = sH[row*NPAD + f] + acc[r] + bb;
          sH[row*NPAD + f] = hn;
          sAf[row*136 + f] = (_Float16)hn;
        }
      }
    }
    __syncthreads();
  }

  // ---------------- readout ----------------
  float* rw = (float*)sWA;                     // out_w1 [100][50] fp32
  for (int i = tid; i < 5000; i += NTHREADS) rw[i] = out_w1[i];
  if (tid < 50){ sB2l[tid] = out_b1[tid]; sBlv[tid] = out_w2[tid]; }
  __syncthreads();
  float ob2 = out_b2[0];
  float partial = 0.0f;
  for (int t = 0; t < 2; t++){
    int a = wv*2 + t;
    float u = 0.0f;
    if (lane < 50){
      u = sB2l[lane];
      #pragma unroll 4
      for (int c = 0; c < FEAT; c++)
        u += sH[a*NPAD + c] * rw[c*50 + lane];
      u = sspf(u) * sBlv[lane];
    }
    #pragma unroll
    for (int s = 1; s < 64; s <<= 1) u += __shfl_xor(u, s);
    partial += u + ob2;
  }
  if (lane == 0) sPart[wv] = partial;
  __syncthreads();
  if (tid == 0){
    float s = 0.0f;
    #pragma unroll
    for (int i = 0; i < NWAVES; i++) s += sPart[i];
    out[mol] = s;
  }
}

extern "C" void kernel_launch(void* const* d_in, const int* in_sizes, int n_in,
                              void* d_out, int out_size, void* d_ws, size_t ws_size,
                              hipStream_t stream)
{
  const int*   z      = (const int*)  d_in[0];
  const float* pos    = (const float*)d_in[1];
  /* d_in[2] = ptr: molecules are fixed 32-atom blocks; unused */
  const float* emb    = (const float*)d_in[3];
  const float* mlp_w1 = (const float*)d_in[4];
  const float* mlp_b1 = (const float*)d_in[5];
  const float* mlp_w2 = (const float*)d_in[6];
  const float* mlp_b2 = (const float*)d_in[7];
  const float* lin1_w = (const float*)d_in[8];
  const float* lin2_w = (const float*)d_in[9];
  const float* lin2_b = (const float*)d_in[10];
  const float* lin_w  = (const float*)d_in[11];
  const float* lin_b  = (const float*)d_in[12];
  const float* out_w1 = (const float*)d_in[13];
  const float* out_b1 = (const float*)d_in[14];
  const float* out_w2 = (const float*)d_in[15];
  const float* out_b2 = (const float*)d_in[16];

  _Float16* wfrag = (_Float16*)d_ws;                    // 344064 B
  float*    tbl   = (float*)((char*)d_ws + WTOTAL*2);   // 4*1024*128*4 = 2 MB

  prep_all<<<PREP_BLOCKS + TBL_BLOCKS, 256, 0, stream>>>(
      lin1_w, lin2_w, lin_w, mlp_w1, mlp_b1, mlp_w2, mlp_b2, wfrag, tbl);
  schnet_mega<<<NMOL, NTHREADS, 0, stream>>>(z, pos, emb, wfrag, tbl,
      lin2_b, lin_b, out_w1, out_b1, out_w2, out_b2, (float*)d_out);
}

// Round 9
// 174.828 us; speedup vs baseline: 1.1521x; 1.1521x over previous
//
#include <hip/hip_runtime.h>
#include <math.h>

#define APM   32
#define NMOL  256
#define FEAT  100
#define NPAD  112
#define LAYERS 4
#define NTHREADS 1024
#define NWAVES   16
#define G_TBL 1024
#define TSTR  128            // table row stride (f32 elems)
#define X1STR 132            // sX1 row stride (f32 elems)

typedef _Float16 f16x8 __attribute__((ext_vector_type(8)));
typedef float    f32x4 __attribute__((ext_vector_type(4)));

// per-layer f16 frag-weight block layout in ws (element offsets)
#define L1F_OFF 0        // lin1f  14336
#define L2F_OFF 14336    // lin2f  14336
#define LVF_OFF 28672    // linf   14336
#define LWTOT   43008    // per layer
#define WTOTAL  (4*LWTOT) // 172032 f16 = 344064 B

#define PREP_BLOCKS 672  // 172032/256
#define TBL_BLOCKS  128  // 32 per layer, 32 s-points per block

__device__ __forceinline__ float sspf(float x){
  // ssp(x) = log(1+e^x) - log2 (direct form, R5)
  return __logf(1.0f + __expf(x)) - 0.69314718056f;
}

// ---------------------------------------------------------------------------
// Single prep launch (R7). Blocks [0,672): weight->MFMA-B-frag conversion
// (validated R3 layout). Blocks [672,800): edge-filter table build with
// w1/w2/biases LDS-staged, 32 grid points per block:
//   tbl[l][s][f] = cc(d_s) * ( ssp(ea(d_s)@W1 + b1) @ W2 + b2 )[f]
// f in [100,128) stored 0 so gather feature-pad lanes read exact zeros.
// ---------------------------------------------------------------------------
__global__ __launch_bounds__(256) void prep_all(
    const float* __restrict__ lin1_w, const float* __restrict__ lin2_w,
    const float* __restrict__ lin_w,
    const float* __restrict__ mlp_w1, const float* __restrict__ mlp_b1,
    const float* __restrict__ mlp_w2, const float* __restrict__ mlp_b2,
    _Float16* __restrict__ outw, float* __restrict__ tbl)
{
  if (blockIdx.x < PREP_BLOCKS){
    int gid = blockIdx.x*256 + threadIdx.x;    // < 172032 exactly
    int l = gid / LWTOT;
    int r = gid - l*LWTOT;
    const float* W; int e;
    if (r < 14336)      { W = lin1_w + l*10000; e = r; }
    else if (r < 28672) { W = lin2_w + l*10000; e = r - 14336; }
    else                { W = lin_w  + l*10000; e = r - 28672; }
    int j = e & 7, L = (e >> 3) & 63, tile = e >> 9;
    int kc = tile / 7, nt = tile - kc*7;
    int k = kc*32 + ((L >> 4) << 3) + j;
    int f = nt*16 + (L & 15);
    float v = (k < 100 && f < FEAT) ? W[k*FEAT + f] : 0.0f;
    outw[gid] = (_Float16)v;
    return;
  }
  // ---- table segment ----
  __shared__ float sW2[10000];
  __shared__ float sW1[2500];
  __shared__ float sB1[100], sB2[100];
  __shared__ float sT[4][100];
  int bid = blockIdx.x - PREP_BLOCKS;
  int l = bid >> 5;                        // 32 blocks per layer
  int s0 = (bid & 31) * 32;
  int tid = threadIdx.x, wv = tid >> 6, lane = tid & 63;
  for (int i = tid; i < 10000; i += 256) sW2[i] = mlp_w2[l*10000 + i];
  for (int i = tid; i < 2500;  i += 256) sW1[i] = mlp_w1[l*2500 + i];
  if (tid < 100) sB1[tid] = mlp_b1[l*100 + tid];
  if (tid >= 128 && tid < 228) sB2[tid-128] = mlp_b2[l*100 + tid-128];
  __syncthreads();
  #pragma unroll 1
  for (int si = 0; si < 8; si++){
    int s = s0 + wv*8 + si;
    float d = 6.0f * (float)s / (float)(G_TBL - 1);
    float ea[25];
    #pragma unroll
    for (int g = 0; g < 25; g++){
      float u = d - 0.25f*(float)g;
      ea[g] = __expf(-8.0f*u*u);
    }
    #pragma unroll
    for (int kk = 0; kk < 2; kk++){
      int k = lane + kk*64;
      if (k < 100){
        float acc = sB1[k];
        #pragma unroll
        for (int g = 0; g < 25; g++)
          acc += ea[g] * sW1[g*100 + k];
        sT[wv][k] = sspf(acc);
      }
    }
    // wave-local LDS RAW: in-order DS + compiler lgkmcnt (validated R6)
    float cc = 0.5f*(__cosf(d*0.52359877559f) + 1.0f);
    #pragma unroll
    for (int ff = 0; ff < 2; ff++){
      int f = lane + ff*64;
      float o = 0.0f;
      if (f < 100){
        o = sB2[f];
        for (int k = 0; k < 100; k++)
          o += sT[wv][k] * sW2[k*100 + f];
        o *= cc;
      }
      tbl[((size_t)l*G_TBL + s)*TSTR + f] = o;   // f in [100,128) -> 0
    }
  }
}

__device__ __forceinline__ void cpw(_Float16* dst, const _Float16* src, int n16){
  const uint4* s = (const uint4*)src;
  uint4* d = (uint4*)dst;
  for (int i = threadIdx.x; i < n16; i += NTHREADS) d[i] = s[i];
}

// ---------------------------------------------------------------------------
// Whole network per molecule in one block. 1024 thr = 16 waves, 1 block/CU.
// R8 regressed 73->108us: gather restructure (b64 pairs, 8 in-flight loads,
// 2 serial atoms/wave) exposed L2 latency (~1GB/dispatch of table reads) —
// +35us of all-pipes-idle stall. R9 gather: HALF-WAVE layout — each 32-lane
// half owns one atom (a = wv*2 + (lane>>5)), each lane 4 features
// {L,L+32,L+64,L+96}. Per round: 32 scalar loads in flight covering BOTH
// atoms; serial depth 8 rounds/wave/layer (was 16); s/frv computed once for
// two atoms; x1 LDS reads are half-broadcast. NaN-safe (R7 lesson): sX1 pad
// cols zeroed once, tbl cols>=100 exact 0, gather writes sAf cols 0..127
// (k-pad refresh). Phase A deleted: lin1f(l+1)+biases(l+1, double-buffered)
// staged inside phase E -> 4 barriers/layer.
// MFMA layouts (validated R3): A: m=lane&15,k=(lane>>4)*8+j ; C/D:
// n=lane&15, m=(lane>>4)*4+r.
// ---------------------------------------------------------------------------
__global__ __launch_bounds__(1024)
__attribute__((amdgpu_waves_per_eu(4, 4)))
void schnet_mega(
    const int* __restrict__ z, const float* __restrict__ pos,
    const float* __restrict__ emb, const _Float16* __restrict__ wf,
    const float* __restrict__ tbl,
    const float* __restrict__ lin2_b, const float* __restrict__ lin_b,
    const float* __restrict__ out_w1, const float* __restrict__ out_b1,
    const float* __restrict__ out_w2, const float* __restrict__ out_b2,
    float* __restrict__ out)
{
  __shared__ __align__(16) _Float16 sWA[43008];     // lin1f|lin2f|linf (86KB)
  __shared__ __align__(16) _Float16 sAf[APM*136];   // A-frag f16 (h / agg)
  __shared__ __align__(16) _Float16 sBf[APM*136];   // A-frag f16 (t2)
  __shared__ __align__(16) float    sX1[APM*X1STR]; // x1 fp32 row-major
  __shared__ __align__(16) float    sH [APM*NPAD];  // h state fp32
  __shared__ float sD [APM*33];
  __shared__ float sB2l[2][NPAD], sBlv[2][NPAD];    // double-buffered biases
  __shared__ float sPos[APM*3];
  __shared__ float sPart[NWAVES];

  int tid = threadIdx.x, lane = tid & 63, wv = tid >> 6;
  int q = lane >> 4, n = lane & 15;
  int mol = blockIdx.x, mb = mol*APM;

  // ---------------- init (+ layer-0 weight/bias prologue) ----------------
  if (tid < 96) sPos[tid] = pos[mb*3 + tid];
  if (tid < 512){                              // zero sBf k-pad cols 112..127
    int r0 = tid >> 4, c0 = 112 + (tid & 15);
    sBf[r0*136 + c0] = (_Float16)0.0f;
  }
  for (int i = tid; i < APM*20; i += NTHREADS){ // zero sX1 pad cols 112..131
    int r = i/20, c = 112 + (i - r*20);
    sX1[r*X1STR + c] = 0.0f;
  }
  for (int i = tid; i < APM*136; i += NTHREADS){ // h init (fp32 + f16 frag)
    int r = i/136, c = i - r*136;
    float v = (c < FEAT) ? emb[z[mb+r]*FEAT + c] : 0.0f;
    sAf[i] = (_Float16)v;
    if (c < NPAD) sH[r*NPAD + c] = v;
  }
  cpw(sWA, wf + L1F_OFF, 14336/8);             // lin1f layer 0
  if (tid < 224){                              // biases layer 0 -> buf 0
    int w = tid/112, i = tid - w*112;
    float v = (i < FEAT) ? (w==0 ? lin2_b : lin_b)[i] : 0.0f;
    (w==0 ? sB2l[0] : sBlv[0])[i] = v;
  }
  __syncthreads();
  for (int p = tid; p < APM*APM; p += NTHREADS){  // distances
    int i = p >> 5, j = p & 31;
    float dx = sPos[i*3+0]-sPos[j*3+0];
    float dy = sPos[i*3+1]-sPos[j*3+1];
    float dz = sPos[i*3+2]-sPos[j*3+2];
    float d2 = dx*dx + dy*dy + dz*dz;
    sD[i*33+j] = (d2 > 36.0f) ? 6.0f : sqrtf(d2);
  }
  __syncthreads();
  if (tid < APM){                  // drop self + 3 farthest: d := 6.0 (tbl=0)
    float dd[32];
    #pragma unroll
    for (int j = 0; j < 32; j++) dd[j] = sD[tid*33+j];
    dd[tid] = 1e30f;
    unsigned dropped = 0u;
    for (int rr = 0; rr < 4; rr++){
      float mx = -1.0f; int mj = 0;
      #pragma unroll
      for (int j = 0; j < 32; j++){
        bool ok = !((dropped>>j)&1u) && (dd[j] > mx);
        mx = ok ? dd[j] : mx;  mj = ok ? j : mj;
      }
      dropped |= 1u << mj;
    }
    #pragma unroll
    for (int j = 0; j < 32; j++)
      if ((dropped>>j)&1u) sD[tid*33+j] = 6.0f;
  }
  __syncthreads();

  // ---------------- interaction layers (4 barriers each) ----------------
  for (int l = 0; l < LAYERS; l++){
    const _Float16* wl = wf + l*LWTOT;
    const float* tb = tbl + (size_t)l*G_TBL*TSTR;
    int cur = l & 1;
    // ---- B: x1 = h @ lin1 -> sX1 row-major fp32 ----
    for (int tau = wv; tau < 14; tau += NWAVES){
      int mt = tau/7, nt = tau - mt*7;
      f32x4 acc = {0.0f,0.0f,0.0f,0.0f};
      #pragma unroll
      for (int kc = 0; kc < 4; kc++){
        f16x8 a = *(const f16x8*)&sAf[(mt*16+n)*136 + kc*32 + q*8];
        f16x8 b = *(const f16x8*)&sWA[((kc*7+nt)*64 + lane)*8];
        acc = __builtin_amdgcn_mfma_f32_16x16x32_f16(a, b, acc, 0, 0, 0);
      }
      #pragma unroll
      for (int r = 0; r < 4; r++)
        sX1[(mt*16+q*4+r)*X1STR + nt*16+n] = acc[r];
    }
    __syncthreads();
    // ---- C: stage lin2f+linf (overlaps gather) + half-wave table gather --
    cpw(sWA + 14336, wl + L2F_OFF, 28672/8);
    {
      int half = lane >> 5, L = lane & 31;
      int a = wv*2 + half;
      int arow = a*33;
      float agg0=0.0f, agg1=0.0f, agg2=0.0f, agg3=0.0f;
      #pragma unroll 1
      for (int j0 = 0; j0 < 32; j0 += 4){
        int off[4]; float frv[4];
        #pragma unroll
        for (int u = 0; u < 4; u++){
          float d = sD[arow + j0 + u];       // 2 distinct addrs per wave
          float un = d * (float)((G_TBL-1)/6.0);
          int s = (int)un;
          s = (s > G_TBL-2) ? (G_TBL-2) : s;
          frv[u] = un - (float)s;
          off[u] = s*TSTR + L;
        }
        float w0[4][4], w1[4][4];            // 32 loads in flight
        #pragma unroll
        for (int u = 0; u < 4; u++){
          #pragma unroll
          for (int c = 0; c < 4; c++){
            w0[u][c] = tb[off[u] + c*32];
            w1[u][c] = tb[off[u] + TSTR + c*32];
          }
        }
        #pragma unroll
        for (int u = 0; u < 4; u++){
          int xb = (j0+u)*X1STR + L;         // same addr both halves: bcast
          agg0 += (w0[u][0] + frv[u]*(w1[u][0]-w0[u][0])) * sX1[xb];
          agg1 += (w0[u][1] + frv[u]*(w1[u][1]-w0[u][1])) * sX1[xb+32];
          agg2 += (w0[u][2] + frv[u]*(w1[u][2]-w0[u][2])) * sX1[xb+64];
          agg3 += (w0[u][3] + frv[u]*(w1[u][3]-w0[u][3])) * sX1[xb+96];
        }
      }
      int ab = a*136 + L;                    // cols 0..127: agg + k-pad(0)
      sAf[ab]    = (_Float16)agg0;
      sAf[ab+32] = (_Float16)agg1;
      sAf[ab+64] = (_Float16)agg2;
      sAf[ab+96] = (_Float16)agg3;
    }
    __syncthreads();
    // ---- D: t2 = ssp(agg @ lin2 + b2l) -> sBf f16 ----
    for (int tau = wv; tau < 14; tau += NWAVES){
      int mt = tau/7, nt = tau - mt*7;
      f32x4 acc = {0.0f,0.0f,0.0f,0.0f};
      #pragma unroll
      for (int kc = 0; kc < 4; kc++){
        f16x8 a = *(const f16x8*)&sAf[(mt*16+n)*136 + kc*32 + q*8];
        f16x8 b = *(const f16x8*)&sWA[14336 + ((kc*7+nt)*64 + lane)*8];
        acc = __builtin_amdgcn_mfma_f32_16x16x32_f16(a, b, acc, 0, 0, 0);
      }
      float bb = sB2l[cur][nt*16+n];
      #pragma unroll
      for (int r = 0; r < 4; r++)
        sBf[(mt*16+q*4+r)*136 + nt*16+n] = (_Float16)sspf(acc[r] + bb);
    }
    __syncthreads();
    // ---- E: v = t2 @ lin + bl ; h += v ; sAf = f16(h)
    //         + prefetch lin1f(l+1) and biases(l+1) (disjoint sWA region) --
    for (int tau = wv; tau < 14; tau += NWAVES){
      int mt = tau/7, nt = tau - mt*7;
      f32x4 acc = {0.0f,0.0f,0.0f,0.0f};
      #pragma unroll
      for (int kc = 0; kc < 4; kc++){
        f16x8 a = *(const f16x8*)&sBf[(mt*16+n)*136 + kc*32 + q*8];
        f16x8 b = *(const f16x8*)&sWA[28672 + ((kc*7+nt)*64 + lane)*8];
        acc = __builtin_amdgcn_mfma_f32_16x16x32_f16(a, b, acc, 0, 0, 0);
      }
      int f = nt*16 + n;
      if (f < FEAT){
        float bb = sBlv[cur][f];
        #pragma unroll
        for (int r = 0; r < 4; r++){
          int row = mt*16 + q*4 + r;
          float hn = sH[row*NPAD + f] + acc[r] + bb;
          sH[row*NPAD + f] = hn;
          sAf[row*136 + f] = (_Float16)hn;
        }
      }
    }
    if (l < LAYERS-1){
      cpw(sWA, wl + LWTOT + L1F_OFF, 14336/8);   // lin1f(l+1) -> sWA[0:14336]
      if (tid < 224){
        int w = tid/112, i = tid - w*112;
        float v = (i < FEAT) ? (w==0 ? lin2_b : lin_b)[(l+1)*FEAT + i] : 0.0f;
        (w==0 ? sB2l[cur^1] : sBlv[cur^1])[i] = v;
      }
    }
    __syncthreads();
  }

  // ---------------- readout ----------------
  float* rw = (float*)sWA;                     // out_w1 [100][50] fp32
  for (int i = tid; i < 5000; i += NTHREADS) rw[i] = out_w1[i];
  if (tid < 50){ sB2l[0][tid] = out_b1[tid]; sBlv[0][tid] = out_w2[tid]; }
  __syncthreads();
  float ob2 = out_b2[0];
  float partial = 0.0f;
  for (int t = 0; t < 2; t++){
    int a = wv*2 + t;
    float u = 0.0f;
    if (lane < 50){
      u = sB2l[0][lane];
      #pragma unroll 4
      for (int c = 0; c < FEAT; c++)
        u += sH[a*NPAD + c] * rw[c*50 + lane];
      u = sspf(u) * sBlv[0][lane];
    }
    #pragma unroll
    for (int s = 1; s < 64; s <<= 1) u += __shfl_xor(u, s);
    partial += u + ob2;
  }
  if (lane == 0) sPart[wv] = partial;
  __syncthreads();
  if (tid == 0){
    float s = 0.0f;
    #pragma unroll
    for (int i = 0; i < NWAVES; i++) s += sPart[i];
    out[mol] = s;
  }
}

extern "C" void kernel_launch(void* const* d_in, const int* in_sizes, int n_in,
                              void* d_out, int out_size, void* d_ws, size_t ws_size,
                              hipStream_t stream)
{
  const int*   z      = (const int*)  d_in[0];
  const float* pos    = (const float*)d_in[1];
  /* d_in[2] = ptr: molecules are fixed 32-atom blocks; unused */
  const float* emb    = (const float*)d_in[3];
  const float* mlp_w1 = (const float*)d_in[4];
  const float* mlp_b1 = (const float*)d_in[5];
  const float* mlp_w2 = (const float*)d_in[6];
  const float* mlp_b2 = (const float*)d_in[7];
  const float* lin1_w = (const float*)d_in[8];
  const float* lin2_w = (const float*)d_in[9];
  const float* lin2_b = (const float*)d_in[10];
  const float* lin_w  = (const float*)d_in[11];
  const float* lin_b  = (const float*)d_in[12];
  const float* out_w1 = (const float*)d_in[13];
  const float* out_b1 = (const float*)d_in[14];
  const float* out_w2 = (const float*)d_in[15];
  const float* out_b2 = (const float*)d_in[16];

  _Float16* wfrag = (_Float16*)d_ws;                    // 344064 B
  float*    tbl   = (float*)((char*)d_ws + WTOTAL*2);   // 4*1024*128*4 = 2 MB

  prep_all<<<PREP_BLOCKS + TBL_BLOCKS, 256, 0, stream>>>(
      lin1_w, lin2_w, lin_w, mlp_w1, mlp_b1, mlp_w2, mlp_b2, wfrag, tbl);
  schnet_mega<<<NMOL, NTHREADS, 0, stream>>>(z, pos, emb, wfrag, tbl,
      lin2_b, lin_b, out_w1, out_b1, out_w2, out_b2, (float*)d_out);
}